// Round 6
// baseline (85.283 us; speedup 1.0000x reference)
//
#include <hip/hip_runtime.h>

// ---------------------------------------------------------------------------
// KAN conv, fully fused (round 6):
//   out[b,o,oh,ow] = sum_{di,dj,j,c} feat_j(x[b,c,oh+di-1,ow+dj-1]) * Wb[o,pos,j,c] + bias[o]
//   feat_0 = silu(t), feat_1..8 = cubic B-spline bases (t=0 outside image —
//   basis(0) != 0, so border cells are computed, not skipped)
// kan_prep : fold Wb[o][pos][j][c] bf16 (331,776 B in d_ws)
// kan_fused: grid 512 = (b 8) x (oh 32) x (o-half 2), 512 thr = 8 waves.
//   Phase A: stage 3 x-rows -> LDS (1 barrier), then 408 threads each compute
//            (row, cell, c-group-of-8): 8 channels x 9 features, written as
//            9 x ds_write_b128 (vs R5's 9 scalar b16/thread: 8x fewer LDS
//            write instructions, 2 barriers total vs 6).
//   Phase B: wave = O16 x M32 (2 acc), 4-way K-split over 81 ksteps of 32;
//            A-frags from LDS (2-way bank alias = free), Wb from global
//            (L2-hot, read exactly once per block), mfma 16x16x32 bf16.
//   Phase C: cross-wave reduce via dead feat LDS, + bias, direct stores.
// LDS: feat 60,384 + xs 12,672 = 73,056 B -> 2 blocks/CU, 4 waves/SIMD.
// ---------------------------------------------------------------------------

typedef __attribute__((ext_vector_type(8))) short v8s;
typedef __attribute__((ext_vector_type(4))) float v4f;
typedef unsigned short ushort_t;

#define WB_ELEMS    (64u * 2592u)        // 165,888 bf16
#define CELL_STRIDE 296                  // ushort elems/cell = 592 B (16B mult)
#define ROW_STRIDE  (34 * CELL_STRIDE)   // 10,064 elems = 20,128 B

__device__ __forceinline__ unsigned short f2bf(float v) {
  union { float f; unsigned int u; } w; w.f = v;
  unsigned int r = w.u + 0x7FFFu + ((w.u >> 16) & 1u);   // RNE
  return (unsigned short)(r >> 16);
}

// ---------------------------------------------------------------------------
// Kernel 1: fold weights  Wb[o][pos][j][c] = (j==0 ? sb : ssp*coef[j-1]), bf16
// ---------------------------------------------------------------------------
__global__ __launch_bounds__(256) void kan_prep(const float* __restrict__ coef,
                                                const float* __restrict__ sb,
                                                const float* __restrict__ ssp,
                                                ushort_t* __restrict__ Wb) {
  int i = blockIdx.x * 256 + threadIdx.x;
  if (i >= (int)WB_ELEMS) return;
  int o = i / 2592;
  int r = i - o * 2592;
  int pos = r / 288;
  int rj = r - pos * 288;
  int j = rj >> 5;
  int c = rj & 31;
  int sidx = (o * 32 + c) * 9 + pos;
  float val = (j == 0) ? sb[sidx] : ssp[sidx] * coef[sidx * 8 + (j - 1)];
  Wb[i] = f2bf(val);
}

// ---------------------------------------------------------------------------
// K-loop over flat step s = di*27 + dj*9 + kk; all offsets compile-time.
// ---------------------------------------------------------------------------
template <int LO, int HI>
__device__ __forceinline__ void kloop(const ushort_t* __restrict__ fb,
                                      const ushort_t* __restrict__ wp,
                                      v4f& acc0, v4f& acc1) {
#pragma unroll
  for (int s = LO; s < HI; ++s) {
    const int di = s / 27;
    const int dj = (s / 9) % 3;
    const int kk = s % 9;
    const int fo = di * ROW_STRIDE + dj * CELL_STRIDE + kk * 32;
    v8s wf = *(const v8s*)(wp + s * 32);
    v8s a0 = *(const v8s*)(fb + fo);
    v8s a1 = *(const v8s*)(fb + fo + 16 * CELL_STRIDE);
    acc0 = __builtin_amdgcn_mfma_f32_16x16x32_bf16(wf, a0, acc0, 0, 0, 0);
    acc1 = __builtin_amdgcn_mfma_f32_16x16x32_bf16(wf, a1, acc1, 0, 0, 0);
  }
}

// ---------------------------------------------------------------------------
// Kernel 2: fused feat + conv + reduce.
// ---------------------------------------------------------------------------
__global__ __launch_bounds__(512, 4) void kan_fused(const float* __restrict__ x,
                                                    const ushort_t* __restrict__ Wb,
                                                    const float* __restrict__ bias,
                                                    float* __restrict__ out) {
  __shared__ ushort_t feat[3 * ROW_STRIDE];   // 60,384 B
  __shared__ float xs[3][32][33];             // 12,672 B (33-word row pad)

  const int tid = threadIdx.x;
  const int bx = blockIdx.x;                  // (b*32 + oh)*2 + ohalf
  const int ohalf = bx & 1;
  const int oh = (bx >> 1) & 31;
  const int b = bx >> 6;

  // ---- Phase A1: stage 3 x-rows (input h = oh-1 .. oh+1) into LDS ----
  {
    int idx = tid * 2;                        // 1024 floats: 32c x 32w
    int c = idx >> 5, w = idx & 31;
    const float* xpc = x + ((b * 32 + c) * 32) * 32 + w;
#pragma unroll
    for (int r = 0; r < 3; ++r) {
      int h = oh + r - 1;
      if (h >= 0 && h < 32) {
        float2 v = *(const float2*)(xpc + h * 32);
        xs[r][c][w] = v.x;
        xs[r][c][w + 1] = v.y;
      }
    }
  }
  __syncthreads();

  // ---- Phase A2: features.  408 threads: (row, cell, c-group of 8). ----
  if (tid < 408) {
    int r = tid / 136;
    int rem = tid - r * 136;
    int cell = rem >> 2;
    int cg = rem & 3;
    int c0 = cg * 8;
    int h = oh + r - 1;
    int wi = cell - 1;
    bool tval = (h >= 0) && (h < 32) && (wi >= 0) && (wi < 32);

    unsigned int pk[9][4];                    // chunk j -> 8 bf16 packed
#pragma unroll
    for (int i = 0; i < 8; ++i) {
      float t = tval ? xs[r][c0 + i][wi] : 0.0f;

      unsigned short us[9];
      us[0] = f2bf(t / (1.0f + __expf(-t)));  // silu
      // cubic uniform B-spline, knots -2.2 + 0.4*i
      float u  = (t + 2.2f) * 2.5f;
      float fi = floorf(u);
      int   iu = (int)fi;
      float s  = u - fi;
      float s2 = s * s, s3 = s2 * s;
      float om = 1.0f - s;
      float w0 = om * om * om * (1.0f / 6.0f);
      float w1 = (4.0f - 6.0f * s2 + 3.0f * s3) * (1.0f / 6.0f);
      float w2 = (1.0f + 3.0f * s + 3.0f * s2 - 3.0f * s3) * (1.0f / 6.0f);
      float w3 = s3 * (1.0f / 6.0f);
#pragma unroll
      for (int jj = 0; jj < 8; ++jj) {
        int d = jj - iu + 3;
        float bv = (d == 0) ? w0 : (d == 1) ? w1 : (d == 2) ? w2 : (d == 3) ? w3 : 0.0f;
        us[jj + 1] = f2bf(bv);
      }
#pragma unroll
      for (int j = 0; j < 9; ++j) {
        unsigned int half = (unsigned int)us[j];
        if (i & 1) pk[j][i >> 1] |= half << 16;
        else       pk[j][i >> 1]  = half;
      }
    }

    ushort_t* dstc = feat + r * ROW_STRIDE + cell * CELL_STRIDE + c0;
#pragma unroll
    for (int j = 0; j < 9; ++j) {
      *(uint4*)(dstc + j * 32) = make_uint4(pk[j][0], pk[j][1], pk[j][2], pk[j][3]);
    }
  }
  __syncthreads();

  // ---- Phase B: MFMA.  wave = (og: O16-group) x M32, kq = K-quarter ----
  const int wv   = tid >> 6;
  const int lane = tid & 63;
  const int row  = lane & 15;
  const int quad = lane >> 4;
  const int og   = wv & 1;
  const int kq   = wv >> 1;
  const int obase = ohalf * 32 + og * 16;

  const ushort_t* fb = feat + row * CELL_STRIDE + quad * 8;
  const ushort_t* wp = Wb + (size_t)(obase + row) * 2592 + quad * 8;

  v4f acc0 = {0.f, 0.f, 0.f, 0.f};
  v4f acc1 = acc0;

  if (kq == 0)      kloop<0, 20>(fb, wp, acc0, acc1);
  else if (kq == 1) kloop<20, 40>(fb, wp, acc0, acc1);
  else if (kq == 2) kloop<40, 60>(fb, wp, acc0, acc1);
  else              kloop<60, 81>(fb, wp, acc0, acc1);

  // ---- Phase C: cross-wave reduce via dead feat LDS, + bias, store ----
  __syncthreads();
  float* red = (float*)feat;                  // 6 groups x 512 fp32 = 12 KB
  if (kq != 0) {
    float* rp = red + ((kq - 1) * 2 + og) * 512 + quad * 4 * 32 + row;
#pragma unroll
    for (int r = 0; r < 4; ++r) {
      rp[r * 32]      = acc0[r];              // pix = row      (m=0)
      rp[r * 32 + 16] = acc1[r];              // pix = 16 + row (m=1)
    }
  }
  __syncthreads();
  if (kq == 0) {
    float* o0 = out + ((size_t)(b * 64 + obase + quad * 4)) * 1024 + oh * 32 + row;
#pragma unroll
    for (int r = 0; r < 4; ++r) {
      float bv = bias[obase + quad * 4 + r];
      float s0 = acc0[r], s1 = acc1[r];
#pragma unroll
      for (int gs = 0; gs < 3; ++gs) {
        const float* rp = red + (gs * 2 + og) * 512 + (quad * 4 + r) * 32 + row;
        s0 += rp[0];
        s1 += rp[16];
      }
      o0[(size_t)r * 1024]      = s0 + bv;
      o0[(size_t)r * 1024 + 16] = s1 + bv;
    }
  }
}

// ---------------------------------------------------------------------------
extern "C" void kernel_launch(void* const* d_in, const int* in_sizes, int n_in,
                              void* d_out, int out_size, void* d_ws, size_t ws_size,
                              hipStream_t stream) {
  const float* x    = (const float*)d_in[0];
  const float* coef = (const float*)d_in[1];
  const float* sb   = (const float*)d_in[2];
  const float* ssp  = (const float*)d_in[3];
  const float* bias = (const float*)d_in[4];
  float* out = (float*)d_out;

  ushort_t* Wb = (ushort_t*)d_ws;             // 331,776 B

  hipLaunchKernelGGL(kan_prep, dim3(648), dim3(256), 0, stream, coef, sb, ssp, Wb);
  hipLaunchKernelGGL(kan_fused, dim3(512), dim3(512), 0, stream, x, Wb, bias, out);
}